// Round 7
// baseline (562.360 us; speedup 1.0000x reference)
//
#include <hip/hip_runtime.h>
#include <math.h>

// LSTM fused: H=32, D=1, B=4096, T=1024 — R19: dual-group intra-wave pipeline.
//
// R17 (279us) law: 655 cyc/step/SIMD = VALU 360 + MFMA 155 + DS 40 + ~120
// barrier/chain stall, serving 4 batch-equiv. R18 (NT=512 same-SIMD pairing)
// REGRESSED: wide barriers cost ~60 cyc/step; stranger-wave phasing can't be
// engineered. R19 keeps R17's parity-pair structure (NT=128, 2-wave barrier)
// and gives each wave TWO independent 4-batch recurrence groups (A,B):
//   [barrier] readA,readB -> mfmaA,mfmaB -> actsA||actsB -> wrA,wrB [barrier]
// Group-B instructions fill group-A's MFMA/exp2 latency shadows (in-order
// issue, independent streams) = guaranteed intra-wave stall filling; barrier
// cost per batch halves (1 per 8 batches). Weights/fragments shared by both
// groups — MFMA (2 tiles/batch), trans (7/state), plain (~20/state) density
// unchanged. 512 blocks x 2 waves = 1 wave/SIMD.
// Acts: rational form, -L/-2L folded (R13/R16): c'=(c*u*v+w*(2-v))/(u*v*w),
// h=(1-m)/((1+e)(1+m)); zero extraction (acc[g][0]); dbuf LDS h exchange.

#define HH 32
#define TT 1024
#define BPB 8               // batches per block: 2 groups of 4
#define NT 128

typedef _Float16 half8 __attribute__((ext_vector_type(8)));
typedef float    f32x4 __attribute__((ext_vector_type(4)));

__global__ __attribute__((amdgpu_flat_work_group_size(NT, NT),
                          amdgpu_waves_per_eu(1, 2)))
void lstm_vp(const float* __restrict__ x,
             const float* __restrict__ W_ih,
             const float* __restrict__ W_hh,
             const float* __restrict__ b_ih,
             const float* __restrict__ b_hh,
             const float* __restrict__ fc_W,
             const float* __restrict__ fc_b,
             float* __restrict__ out)
{
    __shared__ _Float16 xw[BPB * TT];                 // 16 KB: x fp16
    __shared__ __align__(16) _Float16 hx[2][BPB][HH]; // 1 KB: h dbuf
    __shared__ float fo[BPB];                         // epilogue partials

    const int tid  = threadIdx.x;
    const int P    = tid >> 6;           // wave parity: unit 2n+P
    const int lane = tid & 63;
    const int q    = lane >> 4;          // batch index within group (0..3)
    const int n    = lane & 15;          // unit-pair index (0..15)
    const int u    = 2 * n + P;          // owned unit
    const int gb0  = blockIdx.x * BPB;

    // ---- stage the block's 8 x-rows into LDS as fp16 (both waves) ----
    {
        const float4* xg = (const float4*)(x + (size_t)gb0 * TT);
        #pragma unroll
        for (int it = 0; it < (BPB * TT / 4) / NT; ++it) {
            const int idx = it * NT + tid;
            const float4 v = xg[idx];
            _Float16* dst = &xw[idx * 4];
            dst[0] = (_Float16)v.x; dst[1] = (_Float16)v.y;
            dst[2] = (_Float16)v.z; dst[3] = (_Float16)v.w;
        }
    }

    const float L1 = 1.4426950408889634f;    // log2(e)

    // ---- B-fragments (shared by both groups): parity tiles tau = 2g+P.
    //      Col n = W_hh row 32g+2n+P; lane supplies B[k=8q+j][n].
    //      Pre-scaled by -L (i,f,o) / -2L (g). ----
    half8 wf[4];
    #pragma unroll
    for (int g = 0; g < 4; ++g) {
        const float s = (g == 2) ? -2.0f * L1 : -L1;
        const float* arow = W_hh + (size_t)(32 * g + 2 * n + P) * HH + 8 * q;
        #pragma unroll
        for (int j = 0; j < 8; ++j)
            wf[g][j] = (_Float16)(arow[j] * s);
    }

    // ---- per-lane act constants for the single owned unit u (shared) ----
    float wx[4], bb[4];
    #pragma unroll
    for (int g = 0; g < 4; ++g) {
        const float s = (g == 2) ? -2.0f * L1 : -L1;
        wx[g] = W_ih[g * HH + u] * s;
        bb[g] = (b_ih[g * HH + u] + b_hh[g * HH + u]) * s;
    }

    // zero h slot 0 for both groups + staging sync
    hx[0][q][u]     = (_Float16)0.0f;
    hx[0][4 + q][u] = (_Float16)0.0f;
    __syncthreads();

    // A-frag read pointers per group: units 8q..8q+7 of batch (grp*4 + n>>2)
    const half8* hrA0 = (const half8*)&hx[0][n >> 2][8 * q];
    const half8* hrA1 = (const half8*)&hx[1][n >> 2][8 * q];
    const half8* hrB0 = (const half8*)&hx[0][4 + (n >> 2)][8 * q];
    const half8* hrB1 = (const half8*)&hx[1][4 + (n >> 2)][8 * q];

    float cA = 0.0f, hA = 0.0f, cB = 0.0f, hB = 0.0f;

    const half8* xpA = (const half8*)&xw[q * TT];
    const half8* xpB = (const half8*)&xw[(4 + q) * TT];
    half8 xcurA = xpA[0];
    half8 xcurB = xpB[0];

    #pragma unroll 1
    for (int tc = 0; tc < TT / 8; ++tc) {
        const half8 xvA = xcurA;
        const half8 xvB = xcurB;
        const int nc = (tc + 1) & (TT / 8 - 1);
        xcurA = xpA[nc];                  // prefetch next chunk (off-chain)
        xcurB = xpB[nc];

        // pre-convert both chunks to f32 once (off the serial chain)
        float xfA[8], xfB[8];
        #pragma unroll
        for (int j = 0; j < 8; ++j) { xfA[j] = (float)xvA[j]; xfB[j] = (float)xvB[j]; }

        #pragma unroll
        for (int tt = 0; tt < 8; ++tt) {
            // ---- A-frags: one ds_read_b128 per group from current slot ----
            const half8 avA = (tt & 1) ? *hrA1 : *hrA0;
            const half8 avB = (tt & 1) ? *hrB1 : *hrB0;

            // ---- preact input parts, OFF the chain ----
            float qqA[4], qqB[4];
            #pragma unroll
            for (int g = 0; g < 4; ++g) {
                qqA[g] = fmaf(xfA[tt], wx[g], bb[g]);
                qqB[g] = fmaf(xfB[tt], wx[g], bb[g]);
            }

            const f32x4 zero = {0.0f, 0.0f, 0.0f, 0.0f};
            f32x4 accA[4], accB[4];
            #pragma unroll
            for (int g = 0; g < 4; ++g) {
                accA[g] = __builtin_amdgcn_mfma_f32_16x16x32_f16(
                              avA, wf[g], zero, 0, 0, 0);
                asm("" : "+v"(accA[g]));
            }
            #pragma unroll
            for (int g = 0; g < 4; ++g) {
                accB[g] = __builtin_amdgcn_mfma_f32_16x16x32_f16(
                              avB, wf[g], zero, 0, 0, 0);
                asm("" : "+v"(accB[g]));
            }

            // ---- acts, A and B interleaved (independent streams) ----
            const float eaA = __builtin_amdgcn_exp2f(accA[0][0] + qqA[0]);
            const float eaB = __builtin_amdgcn_exp2f(accB[0][0] + qqB[0]);
            const float ebA = __builtin_amdgcn_exp2f(accA[1][0] + qqA[1]);
            const float ebB = __builtin_amdgcn_exp2f(accB[1][0] + qqB[1]);
            const float edA = __builtin_amdgcn_exp2f(accA[2][0] + qqA[2]);
            const float edB = __builtin_amdgcn_exp2f(accB[2][0] + qqB[2]);
            const float eeA = __builtin_amdgcn_exp2f(accA[3][0] + qqA[3]);
            const float eeB = __builtin_amdgcn_exp2f(accB[3][0] + qqB[3]);

            const float uuA = 1.0f + eaA, vvA = 1.0f + edA, wwA = 1.0f + ebA;
            const float uuB = 1.0f + eaB, vvB = 1.0f + edB, wwB = 1.0f + ebB;
            const float uvA = uuA * vvA;
            const float uvB = uuB * vvB;
            const float numA = fmaf(cA, uvA, wwA * (2.0f - vvA));
            const float numB = fmaf(cB, uvB, wwB * (2.0f - vvB));
            cA = numA * __builtin_amdgcn_rcpf(uvA * wwA);
            cB = numB * __builtin_amdgcn_rcpf(uvB * wwB);

            const float mgA = fminf(cA * (-2.0f * L1), 126.0f);
            const float mgB = fminf(cB * (-2.0f * L1), 126.0f);
            const float mA = __builtin_amdgcn_exp2f(mgA);
            const float mB = __builtin_amdgcn_exp2f(mgB);
            hA = (1.0f - mA) * __builtin_amdgcn_rcpf((1.0f + eeA) * (1.0f + mA));
            hB = (1.0f - mB) * __builtin_amdgcn_rcpf((1.0f + eeB) * (1.0f + mB));

            // ---- publish h for next step, flip slot, sync pair ----
            const int ns = (tt & 1) ^ 1;
            hx[ns][q][u]     = (_Float16)hA;
            hx[ns][4 + q][u] = (_Float16)hB;
            __syncthreads();
        }
    }

    // ---- epilogue: out[gb0+bq] = fc_W . h + fc_b across the parity pair ----
    float prA = hA * fc_W[u];
    float prB = hB * fc_W[u];
    #pragma unroll
    for (int d = 1; d <= 8; d <<= 1) {
        prA += __shfl_xor(prA, d, 64);
        prB += __shfl_xor(prB, d, 64);
    }
    if (P == 1 && n == 0) { fo[q] = prA; fo[4 + q] = prB; }
    __syncthreads();
    if (P == 0 && n == 0) {
        out[gb0 + q]     = prA + fo[q]     + fc_b[0];
        out[gb0 + 4 + q] = prB + fo[4 + q] + fc_b[0];
    }
}

extern "C" void kernel_launch(void* const* d_in, const int* in_sizes, int n_in,
                              void* d_out, int out_size, void* d_ws, size_t ws_size,
                              hipStream_t stream) {
    const float* x    = (const float*)d_in[0];
    const float* W_ih = (const float*)d_in[1];
    const float* W_hh = (const float*)d_in[2];
    const float* b_ih = (const float*)d_in[3];
    const float* b_hh = (const float*)d_in[4];
    const float* fc_W = (const float*)d_in[5];
    const float* fc_b = (const float*)d_in[6];
    float* out = (float*)d_out;

    const int B = in_sizes[0] / TT;   // 4096 (D == 1)
    dim3 grid(B / BPB), block(NT);
    lstm_vp<<<grid, block, 0, stream>>>(x, W_ih, W_hh, b_ih, b_hh,
                                        fc_W, fc_b, out);
}

// Round 8
// 284.421 us; speedup vs baseline: 1.9772x; 1.9772x over previous
//
#include <hip/hip_runtime.h>
#include <math.h>

// LSTM fused: H=32, D=1, B=4096, T=1024 — R20: R17 + setprio + chain fusion.
//
// Laws established R12-R19:
//  - Additive pipes per SIMD; only WAVE-level parallelism fills chain stalls
//    (R19: intra-wave dual-stream at 1 w/SIMD = 312 cyc/batch vs R17's 164).
//  - 2048 waves = hard cap at 1 state/lane (131072 states / 64) -> 2 w/SIMD
//    max. Busy-sum floor ~516 cyc/SIMD-step (~220 us).
//  - R17 (279 us): 654 cyc/step = VALU 360 + MFMA 135 + DS 30 + stall 130.
//  - Wide barriers cost (R18: 8-wave barrier +60 cyc). Keep NT=128.
// R20 attacks the 130-cyc stall at fixed structure:
//  1. s_setprio(1) around the ds_read->MFMA critical segment: the 2 resident
//     stranger waves are phase-diverse (T5's paying regime) — the wave in
//     its serial-chain segment outranks the wave doing slack-tolerant acts.
//  2. c->m chain fusion: marg = (num*(-2L))*rc, with num*(-2L) computed in
//     parallel with the rcp — one serial mul removed from the longest chain.
// Everything else identical to R17: parity pair u=2n+P, 4 MFMA tiles/wave
// (tau=2g+P), dbuf LDS h exchange (ds_write_b16/ds_read_b128), rational acts
// with -L/-2L folded, zero extraction acc[g][0], 1024 blocks x 2 waves.

#define HH 32
#define TT 1024
#define BPB 4               // batches per block (= per wave pair)
#define NT 128

typedef _Float16 half8 __attribute__((ext_vector_type(8)));
typedef float    f32x4 __attribute__((ext_vector_type(4)));

__global__ __attribute__((amdgpu_flat_work_group_size(NT, NT),
                          amdgpu_waves_per_eu(2, 2)))
void lstm_vp(const float* __restrict__ x,
             const float* __restrict__ W_ih,
             const float* __restrict__ W_hh,
             const float* __restrict__ b_ih,
             const float* __restrict__ b_hh,
             const float* __restrict__ fc_W,
             const float* __restrict__ fc_b,
             float* __restrict__ out)
{
    __shared__ _Float16 xw[BPB * TT];                 // 8 KB: x fp16
    __shared__ __align__(16) _Float16 hx[2][BPB][HH]; // 512 B: h dbuf
    __shared__ float fo[BPB];                         // epilogue partials

    const int tid  = threadIdx.x;
    const int P    = tid >> 6;           // wave parity: unit 2n+P
    const int lane = tid & 63;
    const int q    = lane >> 4;          // batch index within block (0..3)
    const int n    = lane & 15;          // unit-pair index (0..15)
    const int u    = 2 * n + P;          // owned unit
    const int gb0  = blockIdx.x * BPB;

    // ---- stage the block's 4 x-rows into LDS as fp16 (both waves) ----
    {
        const float4* xg = (const float4*)(x + (size_t)gb0 * TT);
        #pragma unroll
        for (int it = 0; it < (BPB * TT / 4) / NT; ++it) {
            const int idx = it * NT + tid;
            const float4 v = xg[idx];
            _Float16* dst = &xw[idx * 4];
            dst[0] = (_Float16)v.x; dst[1] = (_Float16)v.y;
            dst[2] = (_Float16)v.z; dst[3] = (_Float16)v.w;
        }
    }

    const float L1 = 1.4426950408889634f;    // log2(e)

    // ---- B-fragments: this wave's parity tiles only (tau = 2g+P).
    //      Col n = W_hh row 32g+2n+P; lane supplies B[k=8q+j][n].
    //      Pre-scaled by -L (i,f,o) / -2L (g). ----
    half8 wf[4];
    #pragma unroll
    for (int g = 0; g < 4; ++g) {
        const float s = (g == 2) ? -2.0f * L1 : -L1;
        const float* arow = W_hh + (size_t)(32 * g + 2 * n + P) * HH + 8 * q;
        #pragma unroll
        for (int j = 0; j < 8; ++j)
            wf[g][j] = (_Float16)(arow[j] * s);
    }

    // ---- per-lane act constants for the single owned unit u ----
    float wx[4], bb[4];
    #pragma unroll
    for (int g = 0; g < 4; ++g) {
        const float s = (g == 2) ? -2.0f * L1 : -L1;
        wx[g] = W_ih[g * HH + u] * s;
        bb[g] = (b_ih[g * HH + u] + b_hh[g * HH + u]) * s;
    }

    // zero h slot 0 (each lane covers its own state) + staging sync
    hx[0][q][u] = (_Float16)0.0f;
    __syncthreads();

    // A-frag read pointers: units 8q..8q+7 of batch n>>2 (16B, aligned)
    const half8* hr0 = (const half8*)&hx[0][n >> 2][8 * q];
    const half8* hr1 = (const half8*)&hx[1][n >> 2][8 * q];

    float c = 0.0f, h = 0.0f;

    const half8* xp = (const half8*)&xw[q * TT];
    half8 xcur = xp[0];

    #pragma unroll 1
    for (int tc = 0; tc < TT / 8; ++tc) {
        const half8 xv8 = xcur;
        xcur = xp[(tc + 1) & (TT / 8 - 1)];   // prefetch next chunk (off-chain)

        // pre-convert the chunk to f32 once (off the serial chain)
        float xf[8];
        #pragma unroll
        for (int j = 0; j < 8; ++j) xf[j] = (float)xv8[j];

        #pragma unroll
        for (int tt = 0; tt < 8; ++tt) {
            // ---- critical segment: read + MFMA; boost wave priority so the
            //      phase-diverse partner's act slack yields issue slots ----
            __builtin_amdgcn_s_setprio(1);

            // A-frag: one ds_read_b128 from current slot
            const half8 av = (tt & 1) ? *hr1 : *hr0;

            // preact input part, OFF the chain (fills ds_read shadow)
            const float xv = xf[tt];
            float qq[4];
            #pragma unroll
            for (int g = 0; g < 4; ++g)
                qq[g] = fmaf(xv, wx[g], bb[g]);

            const f32x4 zero = {0.0f, 0.0f, 0.0f, 0.0f};
            f32x4 acc[4];
            #pragma unroll
            for (int g = 0; g < 4; ++g) {
                acc[g] = __builtin_amdgcn_mfma_f32_16x16x32_f16(
                             av, wf[g], zero, 0, 0, 0);
                asm("" : "+v"(acc[g]));   // pin quad to arch VGPRs
            }

            __builtin_amdgcn_s_setprio(0);

            // ---- exp2 args, fixed element 0: zero extraction ----
            const float ea = __builtin_amdgcn_exp2f(acc[0][0] + qq[0]); // e^-i
            const float eb = __builtin_amdgcn_exp2f(acc[1][0] + qq[1]); // e^-f
            const float ed = __builtin_amdgcn_exp2f(acc[2][0] + qq[2]); // e^-2g
            const float ee = __builtin_amdgcn_exp2f(acc[3][0] + qq[3]); // e^-o

            // ---- c' = (c*u*v + w*(2-v)) / (u*v*w); one rcp ----
            const float uu = 1.0f + ea, vv = 1.0f + ed, ww = 1.0f + eb;
            const float uv  = uu * vv;
            const float num = fmaf(c, uv, ww * (2.0f - vv));
            const float tm  = num * (-2.0f * L1);   // off-chain, || with rcp
            const float rc  = __builtin_amdgcn_rcpf(uv * ww);
            c = num * rc;

            // ---- h = (1-m)/((1+e)(1+m)); marg fused: one serial mul less ----
            const float marg = fminf(tm * rc, 126.0f);
            const float m = __builtin_amdgcn_exp2f(marg);
            h = (1.0f - m) * __builtin_amdgcn_rcpf((1.0f + ee) * (1.0f + m));

            // ---- publish h for next step, flip slot, sync pair ----
            hx[(tt & 1) ^ 1][q][u] = (_Float16)h;
            __syncthreads();
        }
    }

    // ---- epilogue: out[gb0+q] = fc_W . h + fc_b across the wave pair ----
    float pr = h * fc_W[u];
    pr += __shfl_xor(pr, 1, 64);
    pr += __shfl_xor(pr, 2, 64);
    pr += __shfl_xor(pr, 4, 64);
    pr += __shfl_xor(pr, 8, 64);
    if (P == 1 && n == 0) fo[q] = pr;
    __syncthreads();
    if (P == 0 && n == 0)
        out[gb0 + q] = pr + fo[q] + fc_b[0];
}

extern "C" void kernel_launch(void* const* d_in, const int* in_sizes, int n_in,
                              void* d_out, int out_size, void* d_ws, size_t ws_size,
                              hipStream_t stream) {
    const float* x    = (const float*)d_in[0];
    const float* W_ih = (const float*)d_in[1];
    const float* W_hh = (const float*)d_in[2];
    const float* b_ih = (const float*)d_in[3];
    const float* b_hh = (const float*)d_in[4];
    const float* fc_W = (const float*)d_in[5];
    const float* fc_b = (const float*)d_in[6];
    float* out = (float*)d_out;

    const int B = in_sizes[0] / TT;   // 4096 (D == 1)
    dim3 grid(B / BPB), block(NT);
    lstm_vp<<<grid, block, 0, stream>>>(x, W_ih, W_hh, b_ih, b_hh,
                                        fc_W, fc_b, out);
}